// Round 11
// baseline (426.593 us; speedup 1.0000x reference)
//
#include <hip/hip_runtime.h>
#include <cmath>

typedef __attribute__((ext_vector_type(8))) short s16x8;   // 8 bf16 = 4 VGPRs (MFMA A/B frag)
typedef __attribute__((ext_vector_type(4))) float f32x4;   // MFMA C/D frag
typedef __attribute__((ext_vector_type(2))) float f32x2;   // packed-f32 (v_pk_fma_f32)

__device__ __forceinline__ short f2bf(float f) {
    union { float f; unsigned u; } v; v.f = f;
    unsigned r = v.u + 0x7FFFu + ((v.u >> 16) & 1u);   // RNE
    return (short)(r >> 16);
}
__device__ __forceinline__ float bf2f(short s) {
    union { unsigned u; float f; } v; v.u = ((unsigned)(unsigned short)s) << 16;
    return v.f;
}
// packed RNE f32x2 -> bf16x2 (1 VALU op per pair; no builtin on gfx950 -> inline asm)
__device__ __forceinline__ unsigned cvtpk2(float lo, float hi) {
    unsigned r;
    asm("v_cvt_pk_bf16_f32 %0, %1, %2" : "=v"(r) : "v"(lo), "v"(hi));
    return r;
}
__device__ __forceinline__ s16x8 cvt8(float4 a, float4 b) {
    union { s16x8 v; unsigned u[4]; } r;
    r.u[0] = cvtpk2(a.x, a.y);
    r.u[1] = cvtpk2(a.z, a.w);
    r.u[2] = cvtpk2(b.x, b.y);
    r.u[3] = cvtpk2(b.z, b.w);
    return r.v;
}
// all-VALU 16-lane (DPP row) shift-reduce sum: result valid in lane r16==0 of each row.
__device__ __forceinline__ float rsum16(float x) {
    int t;
    t = __builtin_amdgcn_update_dpp(0, __builtin_bit_cast(int, x), 0x108, 0xF, 0xF, true);
    x += __builtin_bit_cast(float, t);
    t = __builtin_amdgcn_update_dpp(0, __builtin_bit_cast(int, x), 0x104, 0xF, 0xF, true);
    x += __builtin_bit_cast(float, t);
    t = __builtin_amdgcn_update_dpp(0, __builtin_bit_cast(int, x), 0x102, 0xF, 0xF, true);
    x += __builtin_bit_cast(float, t);
    t = __builtin_amdgcn_update_dpp(0, __builtin_bit_cast(int, x), 0x101, 0xF, 0xF, true);
    x += __builtin_bit_cast(float, t);
    return x;
}

// ---- ws layout ----
// shorts: [w1seqF 4096][w1topF 4096(unused)][w2F 2048][mw1F 20480][mw2F 8192] = 38,912
// floats from float-ofs 19,456: [qc 8192*64]  (ends short-ofs 1,087,488)
// shorts from 1,087,488: [comb_bf16 8192*160] (ends short-ofs 2,398,208)
// ints from short-ofs 2,398,208: [group counters 512] (2 KB)
// shorts from 2,400,256: [emb_bf16 100001*64] (12.8 MB, optional if ws fits)
#define W1SEQ_SH  0
#define W2_SH     8192
#define MW1T_SH   10240
#define MW2T_SH   30720
#define QC_F      19456
#define CB_SH     1087488
#define CNT_SH    2398208
#define EMB_SH    2400256
#define EMB_ROWS  100001
#define EMB_VEC8  800008   // 100001*64/8

// ========== K1: merged prep — qc (blocks 0..127, self-sufficient) + weight prep + emb cvt ====
__global__ __launch_bounds__(256)
void din_prep_kernel(const int* __restrict__ tgt_item,
                     const float* __restrict__ emb,
                     const float* __restrict__ ab1,
                     const float* __restrict__ aw1,
                     const float* __restrict__ aw2,
                     const float* __restrict__ mw1,
                     const float* __restrict__ mw2,
                     short* __restrict__ ws)
{
    const int t = threadIdx.x;
    if (blockIdx.x < 128) {
        // ---- qc = tgt_emb @ aw1_top + ab1 (B-frags rebuilt from aw1 directly) ----
        const int lane = t & 63, wave = t >> 6;
        const int quad = lane >> 4, r16 = lane & 15;
        float* qc = (float*)ws + QC_F;

        const int b0 = (blockIdx.x * 4 + wave) * 16;
        const int it = tgt_item[b0 + r16];
        const float* rp = emb + (size_t)it * 64 + quad * 8;
        float4 v0 = *(const float4*)(rp),      v1 = *(const float4*)(rp + 4);
        float4 v2 = *(const float4*)(rp + 32), v3 = *(const float4*)(rp + 36);
        s16x8 a0 = cvt8(v0, v1);
        s16x8 a1 = cvt8(v2, v3);

        f32x4 acc[4] = {{0,0,0,0},{0,0,0,0},{0,0,0,0},{0,0,0,0}};
        #pragma unroll
        for (int nt = 0; nt < 4; ++nt) {
            const float* colp = aw1 + nt * 16 + r16;
            s16x8 b_0, b_1;
            #pragma unroll
            for (int j = 0; j < 8; ++j) {
                b_0[j] = f2bf(colp[(quad * 8 + j) * 64]);
                b_1[j] = f2bf(colp[(32 + quad * 8 + j) * 64]);
            }
            acc[nt] = __builtin_amdgcn_mfma_f32_16x16x32_bf16(a0, b_0, acc[nt], 0, 0, 0);
            acc[nt] = __builtin_amdgcn_mfma_f32_16x16x32_bf16(a1, b_1, acc[nt], 0, 0, 0);
        }
        #pragma unroll
        for (int nt = 0; nt < 4; ++nt) {
            float bias = ab1[nt * 16 + r16];
            #pragma unroll
            for (int rr = 0; rr < 4; ++rr)   // D: row=quad*4+rr, col=nt*16+r16
                qc[(b0 + quad * 4 + rr) * 64 + nt * 16 + r16] = acc[nt][rr] + bias;
        }
        return;
    }
    if (blockIdx.x >= 192) {         // emb table fp32 -> bf16 (only launched when ws fits)
        const int idx = (blockIdx.x - 192) * 256 + t;   // vec8 index
        if (idx < EMB_VEC8) {
            const float* rp = emb + (size_t)idx * 8;
            float4 v0 = *(const float4*)(rp);
            float4 v1 = *(const float4*)(rp + 4);
            *(s16x8*)(ws + EMB_SH + (size_t)idx * 8) = cvt8(v0, v1);
        }
        return;
    }
    const int bb = blockIdx.x - 128;
    const int g  = bb >> 3;           // region 0..7
    const int sb = bb & 7;            // sub-block within region
    if (g == 0) {                // w1seq frag-linear: frag = nt*2+ks (nt<4,ks<2)
        for (int idx = sb * 512 + t; idx < sb * 512 + 512; idx += 256) {
            int j = idx & 7, lane = (idx >> 3) & 63, fr = idx >> 9;
            int n = (fr >> 1) * 16 + (lane & 15);
            int k = (fr & 1) * 32 + (lane >> 4) * 8 + j;
            ws[W1SEQ_SH + idx] = f2bf(aw1[(64 + k) * 64 + n]);
        }
    } else if (g == 1) {         // zero the 512 group counters (replay-safe)
        if (sb < 2) ((int*)(ws + CNT_SH))[sb * 256 + t] = 0;
    } else if (g == 2) {         // w2 frag-linear: frag = nt*2+ks (nt<2,ks<2)
        int idx = sb * 256 + t;  // 2048 total, exactly 1/thread
        int j = idx & 7, lane = (idx >> 3) & 63, fr = idx >> 9;
        int n = (fr >> 1) * 16 + (lane & 15);
        int k = (fr & 1) * 32 + (lane >> 4) * 8 + j;
        ws[W2_SH + idx] = f2bf(aw2[k * 32 + n]);
    } else if (g == 3) {         // mw2 frag-linear: frag = nt*4+ks (nt<4,ks<4)
        for (int idx = sb * 1024 + t; idx < sb * 1024 + 1024; idx += 256) {
            int j = idx & 7, lane = (idx >> 3) & 63, fr = idx >> 9;
            int n = (fr >> 2) * 16 + (lane & 15);
            int k = (fr & 3) * 32 + (lane >> 4) * 8 + j;
            ws[MW2T_SH + idx] = f2bf(mw2[k * 64 + n]);
        }
    } else {                     // g 4..7: mw1 frag-linear: frag = nt*5+ks (nt<8,ks<5)
        const int base = ((g - 4) * 8 + sb) * 640;   // 32 sub-blocks x 640 = 20480
        for (int ii = t; ii < 640; ii += 256) {
            int idx = base + ii;
            int j = idx & 7, lane = (idx >> 3) & 63, fr = idx >> 9;
            int nt = fr / 5, ks = fr - nt * 5;
            int n = nt * 16 + (lane & 15);
            int k = ks * 32 + (lane >> 4) * 8 + j;
            ws[MW1T_SH + idx] = f2bf(mw1[k * 128 + n]);
        }
    }
}

// ==== K3: fused attention + group-MLP (last-block-done), DPP reductions ====
#define H1_PITCH 72
template<bool TAB>
__global__ __launch_bounds__(256)
void din_att_v8(const int* __restrict__ item_seq,
                const int* __restrict__ seq_len_p,
                const int* __restrict__ tgt_item,
                const float* __restrict__ ctx_feat,
                const float* __restrict__ emb,
                const float* __restrict__ ab2,
                const float* __restrict__ aw3, const float* __restrict__ ab3,
                const float* __restrict__ cw,  const float* __restrict__ cb,
                const float* __restrict__ mb1, const float* __restrict__ mb2,
                const float* __restrict__ mw3, const float* __restrict__ mb3,
                short* __restrict__ ws,
                float* __restrict__ out)
{
    const int t = threadIdx.x, lane = t & 63, wave = t >> 6;
    const int quad = lane >> 4, r16 = lane & 15;
    __shared__ short s_w1[4096];              // 8 KB frag-linear w1seq
    __shared__ short s_h1[4][16 * H1_PITCH];  // 9 KB per-wave H1 roundtrip
    __shared__ float s_sc[4][64];
    __shared__ float s_pool[4][64];
    __shared__ float s_m[4], s_e[4];
    __shared__ short s_mh1[16 * 136];         // 4.3 KB group-MLP layer1
    __shared__ short s_mh2[16 * 72];          // 2.3 KB group-MLP layer2
    __shared__ int   s_last;

    const int b   = blockIdx.x;
    const int len = seq_len_p[b];
    const int tgt = tgt_item[b];

    // ---- stage w1seq frags (linear, conflict-free) ----
    {
        const s16x8* src = (const s16x8*)(ws + W1SEQ_SH);
        s16x8* dst = (s16x8*)s_w1;
        dst[t]       = src[t];
        dst[t + 256] = src[t + 256];
    }

    // ---- gathers: bf16 rows direct from table (or fp32+convert fallback), RETAIN ----
    bool act[4];
    s16x8 af[4][2];
    #pragma unroll
    for (int ci = 0; ci < 4; ++ci) {
        const int c = wave + ci * 4;
        act[ci] = (c < 13) && (c * 16 < len);
        if (act[ci]) {
            int r = c * 16 + r16; if (r > 199) r = 199;
            const int it = item_seq[b * 200 + r];
            if constexpr (TAB) {
                const short* rp = ws + EMB_SH + (size_t)it * 64 + quad * 8;
                af[ci][0] = *(const s16x8*)(rp);
                af[ci][1] = *(const s16x8*)(rp + 32);
            } else {
                const float* rp = emb + (size_t)it * 64 + quad * 8;
                float4 v0 = *(const float4*)(rp),      v1 = *(const float4*)(rp + 4);
                float4 v2 = *(const float4*)(rp + 32), v3 = *(const float4*)(rp + 36);
                af[ci][0] = cvt8(v0, v1);
                af[ci][1] = cvt8(v2, v3);
            }
        }
    }
    // ---- w2 frags from ws (frag-linear, coalesced), qc from ws ----
    s16x8 w2r[4];
    #pragma unroll
    for (int fr = 0; fr < 4; ++fr)
        w2r[fr] = *(const s16x8*)(ws + W2_SH + (fr * 64 + lane) * 8);
    const float* qcp = (const float*)ws + QC_F + b * 64;
    float qcv[4];
    #pragma unroll
    for (int nt = 0; nt < 4; ++nt) qcv[nt] = qcp[nt * 16 + r16];
    const float bias2_lo = ab2[r16], bias2_hi = ab2[16 + r16];
    const float w3_lo    = aw3[r16], w3_hi    = aw3[16 + r16];
    const float b3       = ab3[0];
    __syncthreads();   // weights staged

    short* h1w = s_h1[wave];

    // ---- attention MLP per chunk (wave-independent); raw scores -> per-wave LDS ----
    #pragma unroll
    for (int ci = 0; ci < 4; ++ci) {
        if (!act[ci]) continue;                // wave-uniform branch
        f32x4 acc[4] = {{0,0,0,0},{0,0,0,0},{0,0,0,0},{0,0,0,0}};
        #pragma unroll
        for (int nt = 0; nt < 4; ++nt) {
            s16x8 b_0 = *(const s16x8*)&s_w1[((nt * 2 + 0) * 64 + lane) * 8];
            s16x8 b_1 = *(const s16x8*)&s_w1[((nt * 2 + 1) * 64 + lane) * 8];
            acc[nt] = __builtin_amdgcn_mfma_f32_16x16x32_bf16(af[ci][0], b_0, acc[nt], 0, 0, 0);
            acc[nt] = __builtin_amdgcn_mfma_f32_16x16x32_bf16(af[ci][1], b_1, acc[nt], 0, 0, 0);
        }
        #pragma unroll
        for (int nt = 0; nt < 4; ++nt) {       // D: row=quad*4+rr, col=nt*16+r16
            float v0 = fmaxf(acc[nt][0] + qcv[nt], 0.f);
            float v1 = fmaxf(acc[nt][1] + qcv[nt], 0.f);
            float v2 = fmaxf(acc[nt][2] + qcv[nt], 0.f);
            float v3 = fmaxf(acc[nt][3] + qcv[nt], 0.f);
            unsigned p01 = cvtpk2(v0, v1), p23 = cvtpk2(v2, v3);
            const int col = nt * 16 + r16;
            h1w[(quad * 4 + 0) * H1_PITCH + col] = (short)p01;
            h1w[(quad * 4 + 1) * H1_PITCH + col] = (short)(p01 >> 16);
            h1w[(quad * 4 + 2) * H1_PITCH + col] = (short)p23;
            h1w[(quad * 4 + 3) * H1_PITCH + col] = (short)(p23 >> 16);
        }
        __builtin_amdgcn_wave_barrier();       // wave-local LDS RAW

        s16x8 h0  = *(const s16x8*)&h1w[r16 * H1_PITCH + quad * 8];
        s16x8 h1v = *(const s16x8*)&h1w[r16 * H1_PITCH + 32 + quad * 8];
        f32x4 c2[2] = {{0,0,0,0},{0,0,0,0}};
        #pragma unroll
        for (int nt = 0; nt < 2; ++nt) {
            c2[nt] = __builtin_amdgcn_mfma_f32_16x16x32_bf16(h0,  w2r[nt * 2],     c2[nt], 0, 0, 0);
            c2[nt] = __builtin_amdgcn_mfma_f32_16x16x32_bf16(h1v, w2r[nt * 2 + 1], c2[nt], 0, 0, 0);
        }
        #pragma unroll
        for (int rr = 0; rr < 4; ++rr) {
            float p = fmaxf(c2[0][rr] + bias2_lo, 0.f) * w3_lo
                    + fmaxf(c2[1][rr] + bias2_hi, 0.f) * w3_hi;
            p = rsum16(p);                       // DPP row_shl tree: sum valid in r16==0
            if (r16 == 0) s_sc[wave][ci * 16 + quad * 4 + rr] = p + b3;
        }
        __builtin_amdgcn_wave_barrier();
    }

    // ---- per-wave online softmax; compute exp ONCE, store weight back to s_sc ----
    const int ci_l = lane >> 4;
    const int c_l  = wave + ci_l * 4;
    const int grow = c_l * 16 + r16;
    const bool valid = (c_l < 13) && (grow < len);
    float sc = valid ? s_sc[wave][lane] : -1e30f;
    float m = sc;
    #pragma unroll
    for (int off = 32; off; off >>= 1) m = fmaxf(m, __shfl_xor(m, off));
    float wgt = valid ? __expf(sc - m) : 0.f;
    float e = wgt;
    #pragma unroll
    for (int off = 32; off; off >>= 1) e += __shfl_xor(e, off);
    s_sc[wave][lane] = wgt;                    // overwrite score with weight
    __builtin_amdgcn_wave_barrier();           // wave-local LDS RAW before pooling reads

    // ---- register-retained pooling, packed-f32 accumulate (v_pk_fma_f32) ----
    f32x2 p2[8];
    #pragma unroll
    for (int i = 0; i < 8; ++i) p2[i] = (f32x2){0.f, 0.f};
    #pragma unroll
    for (int ci = 0; ci < 4; ++ci) {
        if (!act[ci]) continue;
        const float w = s_sc[wave][ci * 16 + r16];   // stored weight (0 for invalid rows)
        const f32x2 w2 = {w, w};
        union { s16x8 v; unsigned u[4]; } a0, a1;
        a0.v = af[ci][0]; a1.v = af[ci][1];
        #pragma unroll
        for (int mi = 0; mi < 4; ++mi) {
            f32x2 e0, e1;
            e0[0] = __builtin_bit_cast(float, a0.u[mi] << 16);
            e0[1] = __builtin_bit_cast(float, a0.u[mi] & 0xFFFF0000u);
            e1[0] = __builtin_bit_cast(float, a1.u[mi] << 16);
            e1[1] = __builtin_bit_cast(float, a1.u[mi] & 0xFFFF0000u);
            p2[mi]     += w2 * e0;
            p2[4 + mi] += w2 * e1;
        }
    }
    float pr[16];
    #pragma unroll
    for (int mi = 0; mi < 4; ++mi) {           // DPP row_shl reduce over r16 (rows)
        pr[2 * mi]         = rsum16(p2[mi][0]);
        pr[2 * mi + 1]     = rsum16(p2[mi][1]);
        pr[8 + 2 * mi]     = rsum16(p2[4 + mi][0]);
        pr[8 + 2 * mi + 1] = rsum16(p2[4 + mi][1]);
    }
    if (r16 == 0) {
        #pragma unroll
        for (int j = 0; j < 8; ++j) {
            s_pool[wave][quad * 8 + j]      = pr[j];
            s_pool[wave][32 + quad * 8 + j] = pr[8 + j];
        }
    }
    if (lane == 0) { s_m[wave] = m; s_e[wave] = e; }
    __syncthreads();

    // ---- combine 4 wave-partials (online-softmax merge) + ctx + tgt -> comb ----
    short* comb = ws + CB_SH + b * 160;
    if (t < 64) {
        float gm = fmaxf(fmaxf(s_m[0], s_m[1]), fmaxf(s_m[2], s_m[3]));
        float s0 = __expf(s_m[0] - gm), s1 = __expf(s_m[1] - gm);
        float s2 = __expf(s_m[2] - gm), s3 = __expf(s_m[3] - gm);
        float denom = s0 * s_e[0] + s1 * s_e[1] + s2 * s_e[2] + s3 * s_e[3];
        float pooled = s0 * s_pool[0][t] + s1 * s_pool[1][t]
                     + s2 * s_pool[2][t] + s3 * s_pool[3][t];
        comb[t] = f2bf(pooled / denom);
    } else if (t < 96) {
        const int j = t - 64;
        float a = cb[j];
        #pragma unroll
        for (int k = 0; k < 9; ++k) a += ctx_feat[b * 9 + k] * cw[k * 32 + j];
        comb[128 + j] = f2bf(fmaxf(a, 0.f));
    } else if (t < 160) {
        if constexpr (TAB) {
            comb[64 + (t - 96)] = ws[EMB_SH + (size_t)tgt * 64 + (t - 96)];
        } else {
            comb[64 + (t - 96)] = f2bf(emb[(size_t)tgt * 64 + (t - 96)]);
        }
    }

    // ---- last-block-done group MLP (16 samples/group, split-K-style protocol) ----
    __syncthreads();                 // all comb stores issued+drained (vmcnt0 before barrier)
    if (t == 0) {
        __threadfence();             // device-scope release: comb visible across XCDs
        int* cnt = (int*)(ws + CNT_SH);
        int old = atomicAdd(&cnt[b >> 4], 1);
        s_last = (old == 15) ? 1 : 0;
        if (old == 15) __threadfence();   // acquire side: invalidate stale lines
    }
    __syncthreads();                 // broadcast s_last (block-uniform branch below)
    if (s_last) {
        const int g16 = (b >> 4) * 16;
        const short* combg = ws + CB_SH + (size_t)g16 * 160;
        const short* w1p   = ws + MW1T_SH;
        const short* w2p   = ws + MW2T_SH;

        // layer1: (16x160)@(160x128), K=160 in 5 steps; wave owns nt = 2*wave+{0,1}
        s16x8 am[5];
        #pragma unroll
        for (int ks = 0; ks < 5; ++ks)
            am[ks] = *(const s16x8*)(combg + r16 * 160 + ks * 32 + quad * 8);
        f32x4 macc[2] = {{0,0,0,0},{0,0,0,0}};
        #pragma unroll
        for (int ntl = 0; ntl < 2; ++ntl) {
            const int nt = wave * 2 + ntl;
            #pragma unroll
            for (int ks = 0; ks < 5; ++ks) {
                s16x8 bf = *(const s16x8*)(w1p + ((nt * 5 + ks) * 64 + lane) * 8);
                macc[ntl] = __builtin_amdgcn_mfma_f32_16x16x32_bf16(am[ks], bf, macc[ntl], 0, 0, 0);
            }
        }
        #pragma unroll
        for (int ntl = 0; ntl < 2; ++ntl) {
            const int nt = wave * 2 + ntl;
            float bias = mb1[nt * 16 + r16];
            float v0 = fmaxf(macc[ntl][0] + bias, 0.f);
            float v1 = fmaxf(macc[ntl][1] + bias, 0.f);
            float v2 = fmaxf(macc[ntl][2] + bias, 0.f);
            float v3 = fmaxf(macc[ntl][3] + bias, 0.f);
            unsigned p01 = cvtpk2(v0, v1), p23 = cvtpk2(v2, v3);
            const int col = nt * 16 + r16;
            s_mh1[(quad * 4 + 0) * 136 + col] = (short)p01;
            s_mh1[(quad * 4 + 1) * 136 + col] = (short)(p01 >> 16);
            s_mh1[(quad * 4 + 2) * 136 + col] = (short)p23;
            s_mh1[(quad * 4 + 3) * 136 + col] = (short)(p23 >> 16);
        }
        __syncthreads();

        // layer2: (16x128)@(128x64), K=128 in 4 steps; wave owns nt = wave
        s16x8 a2[4];
        #pragma unroll
        for (int ks = 0; ks < 4; ++ks)
            a2[ks] = *(const s16x8*)&s_mh1[r16 * 136 + ks * 32 + quad * 8];
        f32x4 acc2 = {0,0,0,0};
        {
            const int nt = wave;
            #pragma unroll
            for (int ks = 0; ks < 4; ++ks) {
                s16x8 bf = *(const s16x8*)(w2p + ((nt * 4 + ks) * 64 + lane) * 8);
                acc2 = __builtin_amdgcn_mfma_f32_16x16x32_bf16(a2[ks], bf, acc2, 0, 0, 0);
            }
            float bias = mb2[nt * 16 + r16];
            float v0 = fmaxf(acc2[0] + bias, 0.f);
            float v1 = fmaxf(acc2[1] + bias, 0.f);
            float v2 = fmaxf(acc2[2] + bias, 0.f);
            float v3 = fmaxf(acc2[3] + bias, 0.f);
            unsigned p01 = cvtpk2(v0, v1), p23 = cvtpk2(v2, v3);
            const int col = nt * 16 + r16;
            s_mh2[(quad * 4 + 0) * 72 + col] = (short)p01;
            s_mh2[(quad * 4 + 1) * 72 + col] = (short)(p01 >> 16);
            s_mh2[(quad * 4 + 2) * 72 + col] = (short)p23;
            s_mh2[(quad * 4 + 3) * 72 + col] = (short)(p23 >> 16);
        }
        __syncthreads();

        // layer3: (16x64)@(64x1) + sigmoid — wave 0 only
        if (wave == 0) {
            float p = 0.f;
            #pragma unroll
            for (int j = 0; j < 16; ++j)
                p += bf2f(s_mh2[r16 * 72 + quad * 16 + j]) * mw3[quad * 16 + j];
            p += __shfl_xor(p, 16);
            p += __shfl_xor(p, 32);
            if (quad == 0) out[g16 + r16] = 1.f / (1.f + __expf(-(p + mb3[0])));
        }
    }
}

extern "C" void kernel_launch(void* const* d_in, const int* in_sizes, int n_in,
                              void* d_out, int out_size, void* d_ws, size_t ws_size,
                              hipStream_t stream)
{
    const int*   item_seq  = (const int*)  d_in[0];
    // d_in[1] click_sequence: unused by the reference
    const int*   seq_len   = (const int*)  d_in[2];
    const int*   tgt_item  = (const int*)  d_in[3];
    const float* ctx_feat  = (const float*)d_in[4];
    const float* emb       = (const float*)d_in[5];
    const float* aw1 = (const float*)d_in[6];
    const float* ab1 = (const float*)d_in[7];
    const float* aw2 = (const float*)d_in[8];
    const float* ab2 = (const float*)d_in[9];
    const float* aw3 = (const float*)d_in[10];
    const float* ab3 = (const float*)d_in[11];
    const float* cw  = (const float*)d_in[12];
    const float* cb  = (const float*)d_in[13];
    const float* mw1 = (const float*)d_in[14];
    const float* mb1 = (const float*)d_in[15];
    const float* mw2 = (const float*)d_in[16];
    const float* mb2 = (const float*)d_in[17];
    const float* mw3 = (const float*)d_in[18];
    const float* mb3 = (const float*)d_in[19];
    float* out = (float*)d_out;
    short* ws  = (short*)d_ws;

    const size_t need_bytes = (size_t)(EMB_SH + EMB_ROWS * 64) * sizeof(short);
    const bool tab = ws_size >= need_bytes;

    if (tab) {
        // blocks: [0,128) qc | [128,192) weight regions + counter zero | [192,3318) emb cvt
        hipLaunchKernelGGL(din_prep_kernel, dim3(128 + 64 + 3126), dim3(256), 0, stream,
                           tgt_item, emb, ab1, aw1, aw2, mw1, mw2, ws);
        hipLaunchKernelGGL(din_att_v8<true>, dim3(8192), dim3(256), 0, stream,
                           item_seq, seq_len, tgt_item, ctx_feat, emb,
                           ab2, aw3, ab3, cw, cb, mb1, mb2, mw3, mb3, ws, out);
    } else {
        hipLaunchKernelGGL(din_prep_kernel, dim3(128 + 64), dim3(256), 0, stream,
                           tgt_item, emb, ab1, aw1, aw2, mw1, mw2, ws);
        hipLaunchKernelGGL(din_att_v8<false>, dim3(8192), dim3(256), 0, stream,
                           item_seq, seq_len, tgt_item, ctx_feat, emb,
                           ab2, aw3, ab3, cw, cb, mb1, mb2, mw3, mb3, ws, out);
    }
}

// Round 12
// 161.253 us; speedup vs baseline: 2.6455x; 2.6455x over previous
//
#include <hip/hip_runtime.h>
#include <cmath>

typedef __attribute__((ext_vector_type(8))) short s16x8;   // 8 bf16 = 4 VGPRs (MFMA A/B frag)
typedef __attribute__((ext_vector_type(4))) float f32x4;   // MFMA C/D frag
typedef __attribute__((ext_vector_type(2))) float f32x2;   // packed-f32 (v_pk_fma_f32)

__device__ __forceinline__ short f2bf(float f) {
    union { float f; unsigned u; } v; v.f = f;
    unsigned r = v.u + 0x7FFFu + ((v.u >> 16) & 1u);   // RNE
    return (short)(r >> 16);
}
__device__ __forceinline__ float bf2f(short s) {
    union { unsigned u; float f; } v; v.u = ((unsigned)(unsigned short)s) << 16;
    return v.f;
}
// packed RNE f32x2 -> bf16x2 (1 VALU op per pair; no builtin on gfx950 -> inline asm)
__device__ __forceinline__ unsigned cvtpk2(float lo, float hi) {
    unsigned r;
    asm("v_cvt_pk_bf16_f32 %0, %1, %2" : "=v"(r) : "v"(lo), "v"(hi));
    return r;
}
__device__ __forceinline__ s16x8 cvt8(float4 a, float4 b) {
    union { s16x8 v; unsigned u[4]; } r;
    r.u[0] = cvtpk2(a.x, a.y);
    r.u[1] = cvtpk2(a.z, a.w);
    r.u[2] = cvtpk2(b.x, b.y);
    r.u[3] = cvtpk2(b.z, b.w);
    return r.v;
}
// all-VALU 16-lane (DPP row) shift-reduce sum: result valid in lane r16==0 of each row.
__device__ __forceinline__ float rsum16(float x) {
    int t;
    t = __builtin_amdgcn_update_dpp(0, __builtin_bit_cast(int, x), 0x108, 0xF, 0xF, true);
    x += __builtin_bit_cast(float, t);
    t = __builtin_amdgcn_update_dpp(0, __builtin_bit_cast(int, x), 0x104, 0xF, 0xF, true);
    x += __builtin_bit_cast(float, t);
    t = __builtin_amdgcn_update_dpp(0, __builtin_bit_cast(int, x), 0x102, 0xF, 0xF, true);
    x += __builtin_bit_cast(float, t);
    t = __builtin_amdgcn_update_dpp(0, __builtin_bit_cast(int, x), 0x101, 0xF, 0xF, true);
    x += __builtin_bit_cast(float, t);
    return x;
}

// ---- ws layout ----
// shorts: [w1seqF 4096][w1topF 4096(unused now)][w2F 2048][mw1F 20480][mw2F 8192] = 38,912
// floats from float-ofs 19,456: [qc 8192*64]  (ends short-ofs 1,087,488)
// shorts from 1,087,488: [comb_bf16 8192*160] (ends short-ofs 2,398,208)
// shorts from 2,400,256: [emb_bf16 100001*64] (12.8 MB, optional if ws fits)
#define W1SEQ_SH  0
#define W2_SH     8192
#define MW1T_SH   10240
#define MW2T_SH   30720
#define QC_F      19456
#define CB_SH     1087488
#define EMB_SH    2400256
#define EMB_ROWS  100001
#define EMB_VEC8  800008   // 100001*64/8

// ========== K1: merged prep — qc (blocks 0..127, self-sufficient) + weight prep + emb cvt ====
// qc blocks read ONLY aw1/emb/ab1 inputs (no ws reads) -> no same-launch ordering hazard.
__global__ __launch_bounds__(256)
void din_prep_kernel(const int* __restrict__ tgt_item,
                     const float* __restrict__ emb,
                     const float* __restrict__ ab1,
                     const float* __restrict__ aw1,
                     const float* __restrict__ aw2,
                     const float* __restrict__ mw1,
                     const float* __restrict__ mw2,
                     short* __restrict__ ws)
{
    const int t = threadIdx.x;
    if (blockIdx.x < 128) {
        // ---- qc = tgt_emb @ aw1_top + ab1 (B-frags rebuilt from aw1 directly) ----
        const int lane = t & 63, wave = t >> 6;
        const int quad = lane >> 4, r16 = lane & 15;
        float* qc = (float*)ws + QC_F;

        const int b0 = (blockIdx.x * 4 + wave) * 16;
        const int it = tgt_item[b0 + r16];
        const float* rp = emb + (size_t)it * 64 + quad * 8;
        float4 v0 = *(const float4*)(rp),      v1 = *(const float4*)(rp + 4);
        float4 v2 = *(const float4*)(rp + 32), v3 = *(const float4*)(rp + 36);
        s16x8 a0 = cvt8(v0, v1);
        s16x8 a1 = cvt8(v2, v3);

        f32x4 acc[4] = {{0,0,0,0},{0,0,0,0},{0,0,0,0},{0,0,0,0}};
        #pragma unroll
        for (int nt = 0; nt < 4; ++nt) {
            // frag fr=nt*2+ks: element j = bf16(aw1[(ks*32+quad*8+j)*64 + nt*16+r16])
            const float* colp = aw1 + nt * 16 + r16;
            s16x8 b_0, b_1;
            #pragma unroll
            for (int j = 0; j < 8; ++j) {
                b_0[j] = f2bf(colp[(quad * 8 + j) * 64]);
                b_1[j] = f2bf(colp[(32 + quad * 8 + j) * 64]);
            }
            acc[nt] = __builtin_amdgcn_mfma_f32_16x16x32_bf16(a0, b_0, acc[nt], 0, 0, 0);
            acc[nt] = __builtin_amdgcn_mfma_f32_16x16x32_bf16(a1, b_1, acc[nt], 0, 0, 0);
        }
        #pragma unroll
        for (int nt = 0; nt < 4; ++nt) {
            float bias = ab1[nt * 16 + r16];
            #pragma unroll
            for (int rr = 0; rr < 4; ++rr)   // D: row=quad*4+rr, col=nt*16+r16
                qc[(b0 + quad * 4 + rr) * 64 + nt * 16 + r16] = acc[nt][rr] + bias;
        }
        return;
    }
    if (blockIdx.x >= 192) {         // emb table fp32 -> bf16 (only launched when ws fits)
        const int idx = (blockIdx.x - 192) * 256 + t;   // vec8 index
        if (idx < EMB_VEC8) {
            const float* rp = emb + (size_t)idx * 8;
            float4 v0 = *(const float4*)(rp);
            float4 v1 = *(const float4*)(rp + 4);
            *(s16x8*)(ws + EMB_SH + (size_t)idx * 8) = cvt8(v0, v1);
        }
        return;
    }
    const int bb = blockIdx.x - 128;
    const int g  = bb >> 3;           // region 0..7
    const int sb = bb & 7;            // sub-block within region
    if (g == 0) {                // w1seq frag-linear: frag = nt*2+ks (nt<4,ks<2)
        for (int idx = sb * 512 + t; idx < sb * 512 + 512; idx += 256) {
            int j = idx & 7, lane = (idx >> 3) & 63, fr = idx >> 9;
            int n = (fr >> 1) * 16 + (lane & 15);
            int k = (fr & 1) * 32 + (lane >> 4) * 8 + j;
            ws[W1SEQ_SH + idx] = f2bf(aw1[(64 + k) * 64 + n]);
        }
    } else if (g == 1) {         // (w1top region retired — qc self-converts now; keep g for layout)
        // no-op
    } else if (g == 2) {         // w2 frag-linear: frag = nt*2+ks (nt<2,ks<2)
        int idx = sb * 256 + t;  // 2048 total, exactly 1/thread
        int j = idx & 7, lane = (idx >> 3) & 63, fr = idx >> 9;
        int n = (fr >> 1) * 16 + (lane & 15);
        int k = (fr & 1) * 32 + (lane >> 4) * 8 + j;
        ws[W2_SH + idx] = f2bf(aw2[k * 32 + n]);
    } else if (g == 3) {         // mw2 frag-linear: frag = nt*4+ks (nt<4,ks<4)
        for (int idx = sb * 1024 + t; idx < sb * 1024 + 1024; idx += 256) {
            int j = idx & 7, lane = (idx >> 3) & 63, fr = idx >> 9;
            int n = (fr >> 2) * 16 + (lane & 15);
            int k = (fr & 3) * 32 + (lane >> 4) * 8 + j;
            ws[MW2T_SH + idx] = f2bf(mw2[k * 64 + n]);
        }
    } else {                     // g 4..7: mw1 frag-linear: frag = nt*5+ks (nt<8,ks<5)
        const int base = ((g - 4) * 8 + sb) * 640;   // 32 sub-blocks x 640 = 20480
        for (int ii = t; ii < 640; ii += 256) {
            int idx = base + ii;
            int j = idx & 7, lane = (idx >> 3) & 63, fr = idx >> 9;
            int nt = fr / 5, ks = fr - nt * 5;
            int n = nt * 16 + (lane & 15);
            int k = ks * 32 + (lane >> 4) * 8 + j;
            ws[MW1T_SH + idx] = f2bf(mw1[k * 128 + n]);
        }
    }
}

// ==== K3: fused attention (round-9 structure) + s_setprio around MFMA clusters ====
#define H1_PITCH 72
template<bool TAB>
__global__ __launch_bounds__(256)
void din_att_v7(const int* __restrict__ item_seq,
                const int* __restrict__ seq_len_p,
                const int* __restrict__ tgt_item,
                const float* __restrict__ ctx_feat,
                const float* __restrict__ emb,
                const float* __restrict__ ab2,
                const float* __restrict__ aw3, const float* __restrict__ ab3,
                const float* __restrict__ cw,  const float* __restrict__ cb,
                short* __restrict__ ws)
{
    const int t = threadIdx.x, lane = t & 63, wave = t >> 6;
    const int quad = lane >> 4, r16 = lane & 15;
    __shared__ short s_w1[4096];              // 8 KB frag-linear w1seq
    __shared__ short s_h1[4][16 * H1_PITCH];  // 9 KB per-wave H1 roundtrip
    __shared__ float s_sc[4][64];
    __shared__ float s_pool[4][64];
    __shared__ float s_m[4], s_e[4];

    const int b   = blockIdx.x;
    const int len = seq_len_p[b];
    const int tgt = tgt_item[b];

    // ---- stage w1seq frags (linear, conflict-free) ----
    {
        const s16x8* src = (const s16x8*)(ws + W1SEQ_SH);
        s16x8* dst = (s16x8*)s_w1;
        dst[t]       = src[t];
        dst[t + 256] = src[t + 256];
    }

    // ---- gathers: bf16 rows direct from table (or fp32+convert fallback), RETAIN ----
    bool act[4];
    s16x8 af[4][2];
    #pragma unroll
    for (int ci = 0; ci < 4; ++ci) {
        const int c = wave + ci * 4;
        act[ci] = (c < 13) && (c * 16 < len);
        if (act[ci]) {
            int r = c * 16 + r16; if (r > 199) r = 199;
            const int it = item_seq[b * 200 + r];
            if constexpr (TAB) {
                const short* rp = ws + EMB_SH + (size_t)it * 64 + quad * 8;
                af[ci][0] = *(const s16x8*)(rp);
                af[ci][1] = *(const s16x8*)(rp + 32);
            } else {
                const float* rp = emb + (size_t)it * 64 + quad * 8;
                float4 v0 = *(const float4*)(rp),      v1 = *(const float4*)(rp + 4);
                float4 v2 = *(const float4*)(rp + 32), v3 = *(const float4*)(rp + 36);
                af[ci][0] = cvt8(v0, v1);
                af[ci][1] = cvt8(v2, v3);
            }
        }
    }
    // ---- w2 frags from ws (frag-linear, coalesced), qc from ws ----
    s16x8 w2r[4];
    #pragma unroll
    for (int fr = 0; fr < 4; ++fr)
        w2r[fr] = *(const s16x8*)(ws + W2_SH + (fr * 64 + lane) * 8);
    const float* qcp = (const float*)ws + QC_F + b * 64;
    float qcv[4];
    #pragma unroll
    for (int nt = 0; nt < 4; ++nt) qcv[nt] = qcp[nt * 16 + r16];
    const float bias2_lo = ab2[r16], bias2_hi = ab2[16 + r16];
    const float w3_lo    = aw3[r16], w3_hi    = aw3[16 + r16];
    const float b3       = ab3[0];
    __syncthreads();   // weights staged

    short* h1w = s_h1[wave];

    // ---- attention MLP per chunk (wave-independent); raw scores -> per-wave LDS ----
    #pragma unroll
    for (int ci = 0; ci < 4; ++ci) {
        if (!act[ci]) continue;                // wave-uniform branch
        f32x4 acc[4] = {{0,0,0,0},{0,0,0,0},{0,0,0,0},{0,0,0,0}};
        __builtin_amdgcn_s_setprio(1);
        #pragma unroll
        for (int nt = 0; nt < 4; ++nt) {
            s16x8 b_0 = *(const s16x8*)&s_w1[((nt * 2 + 0) * 64 + lane) * 8];
            s16x8 b_1 = *(const s16x8*)&s_w1[((nt * 2 + 1) * 64 + lane) * 8];
            acc[nt] = __builtin_amdgcn_mfma_f32_16x16x32_bf16(af[ci][0], b_0, acc[nt], 0, 0, 0);
            acc[nt] = __builtin_amdgcn_mfma_f32_16x16x32_bf16(af[ci][1], b_1, acc[nt], 0, 0, 0);
        }
        __builtin_amdgcn_s_setprio(0);
        #pragma unroll
        for (int nt = 0; nt < 4; ++nt) {       // D: row=quad*4+rr, col=nt*16+r16
            float v0 = fmaxf(acc[nt][0] + qcv[nt], 0.f);
            float v1 = fmaxf(acc[nt][1] + qcv[nt], 0.f);
            float v2 = fmaxf(acc[nt][2] + qcv[nt], 0.f);
            float v3 = fmaxf(acc[nt][3] + qcv[nt], 0.f);
            unsigned p01 = cvtpk2(v0, v1), p23 = cvtpk2(v2, v3);
            const int col = nt * 16 + r16;
            h1w[(quad * 4 + 0) * H1_PITCH + col] = (short)p01;
            h1w[(quad * 4 + 1) * H1_PITCH + col] = (short)(p01 >> 16);
            h1w[(quad * 4 + 2) * H1_PITCH + col] = (short)p23;
            h1w[(quad * 4 + 3) * H1_PITCH + col] = (short)(p23 >> 16);
        }
        __builtin_amdgcn_wave_barrier();       // wave-local LDS RAW

        s16x8 h0  = *(const s16x8*)&h1w[r16 * H1_PITCH + quad * 8];
        s16x8 h1v = *(const s16x8*)&h1w[r16 * H1_PITCH + 32 + quad * 8];
        f32x4 c2[2] = {{0,0,0,0},{0,0,0,0}};
        __builtin_amdgcn_s_setprio(1);
        #pragma unroll
        for (int nt = 0; nt < 2; ++nt) {
            c2[nt] = __builtin_amdgcn_mfma_f32_16x16x32_bf16(h0,  w2r[nt * 2],     c2[nt], 0, 0, 0);
            c2[nt] = __builtin_amdgcn_mfma_f32_16x16x32_bf16(h1v, w2r[nt * 2 + 1], c2[nt], 0, 0, 0);
        }
        __builtin_amdgcn_s_setprio(0);
        #pragma unroll
        for (int rr = 0; rr < 4; ++rr) {
            float p = fmaxf(c2[0][rr] + bias2_lo, 0.f) * w3_lo
                    + fmaxf(c2[1][rr] + bias2_hi, 0.f) * w3_hi;
            p = rsum16(p);                       // DPP row_shl tree: sum valid in r16==0
            if (r16 == 0) s_sc[wave][ci * 16 + quad * 4 + rr] = p + b3;
        }
        __builtin_amdgcn_wave_barrier();
    }

    // ---- per-wave online softmax; compute exp ONCE, store weight back to s_sc ----
    const int ci_l = lane >> 4;
    const int c_l  = wave + ci_l * 4;
    const int grow = c_l * 16 + r16;
    const bool valid = (c_l < 13) && (grow < len);
    float sc = valid ? s_sc[wave][lane] : -1e30f;
    float m = sc;
    #pragma unroll
    for (int off = 32; off; off >>= 1) m = fmaxf(m, __shfl_xor(m, off));
    float wgt = valid ? __expf(sc - m) : 0.f;
    float e = wgt;
    #pragma unroll
    for (int off = 32; off; off >>= 1) e += __shfl_xor(e, off);
    s_sc[wave][lane] = wgt;                    // overwrite score with weight
    __builtin_amdgcn_wave_barrier();           // wave-local LDS RAW before pooling reads

    // ---- register-retained pooling, packed-f32 accumulate (v_pk_fma_f32) ----
    f32x2 p2[8];
    #pragma unroll
    for (int i = 0; i < 8; ++i) p2[i] = (f32x2){0.f, 0.f};
    #pragma unroll
    for (int ci = 0; ci < 4; ++ci) {
        if (!act[ci]) continue;
        const float w = s_sc[wave][ci * 16 + r16];   // stored weight (0 for invalid rows)
        const f32x2 w2 = {w, w};
        union { s16x8 v; unsigned u[4]; } a0, a1;
        a0.v = af[ci][0]; a1.v = af[ci][1];
        #pragma unroll
        for (int mi = 0; mi < 4; ++mi) {
            f32x2 e0, e1;
            e0[0] = __builtin_bit_cast(float, a0.u[mi] << 16);
            e0[1] = __builtin_bit_cast(float, a0.u[mi] & 0xFFFF0000u);
            e1[0] = __builtin_bit_cast(float, a1.u[mi] << 16);
            e1[1] = __builtin_bit_cast(float, a1.u[mi] & 0xFFFF0000u);
            p2[mi]     += w2 * e0;
            p2[4 + mi] += w2 * e1;
        }
    }
    float pr[16];
    #pragma unroll
    for (int mi = 0; mi < 4; ++mi) {           // DPP row_shl reduce over r16 (rows)
        pr[2 * mi]         = rsum16(p2[mi][0]);
        pr[2 * mi + 1]     = rsum16(p2[mi][1]);
        pr[8 + 2 * mi]     = rsum16(p2[4 + mi][0]);
        pr[8 + 2 * mi + 1] = rsum16(p2[4 + mi][1]);
    }
    if (r16 == 0) {
        #pragma unroll
        for (int j = 0; j < 8; ++j) {
            s_pool[wave][quad * 8 + j]      = pr[j];
            s_pool[wave][32 + quad * 8 + j] = pr[8 + j];
        }
    }
    if (lane == 0) { s_m[wave] = m; s_e[wave] = e; }
    __syncthreads();   // the only post-entry block barrier

    // ---- combine 4 wave-partials (online-softmax merge) + ctx + tgt -> comb ----
    short* comb = ws + CB_SH + b * 160;
    if (t < 64) {
        float gm = fmaxf(fmaxf(s_m[0], s_m[1]), fmaxf(s_m[2], s_m[3]));
        float s0 = __expf(s_m[0] - gm), s1 = __expf(s_m[1] - gm);
        float s2 = __expf(s_m[2] - gm), s3 = __expf(s_m[3] - gm);
        float denom = s0 * s_e[0] + s1 * s_e[1] + s2 * s_e[2] + s3 * s_e[3];
        float pooled = s0 * s_pool[0][t] + s1 * s_pool[1][t]
                     + s2 * s_pool[2][t] + s3 * s_pool[3][t];
        comb[t] = f2bf(pooled / denom);
    } else if (t < 96) {
        const int j = t - 64;
        float a = cb[j];
        #pragma unroll
        for (int k = 0; k < 9; ++k) a += ctx_feat[b * 9 + k] * cw[k * 32 + j];
        comb[128 + j] = f2bf(fmaxf(a, 0.f));
    } else if (t < 160) {
        if constexpr (TAB) {
            comb[64 + (t - 96)] = ws[EMB_SH + (size_t)tgt * 64 + (t - 96)];
        } else {
            comb[64 + (t - 96)] = f2bf(emb[(size_t)tgt * 64 + (t - 96)]);
        }
    }
}

// ============== K4: batched final MLP via MFMA (4 waves co-own a 16-row group) =====
__global__ __launch_bounds__(256)
void din_mlp_kernel(const float* __restrict__ mb1,
                    const float* __restrict__ mb2,
                    const float* __restrict__ mw3, const float* __restrict__ mb3,
                    const short* __restrict__ ws,
                    float* __restrict__ out)
{
    const int t = threadIdx.x, lane = t & 63, wave = t >> 6;
    const int quad = lane >> 4, r16 = lane & 15;
    __shared__ short s_h1[16 * 136];
    __shared__ short s_h2[16 * 72];

    const int b0 = blockIdx.x * 16;
    const short* comb = ws + CB_SH;
    const short* w1   = ws + MW1T_SH;
    const short* w2   = ws + MW2T_SH;

    // layer1: (16x160) @ (160x128), K=160 in 5 steps; wave owns nt = 2*wave+{0,1}
    s16x8 a[5];
    #pragma unroll
    for (int ks = 0; ks < 5; ++ks)
        a[ks] = *(const s16x8*)(comb + (b0 + r16) * 160 + ks * 32 + quad * 8);
    f32x4 acc[2] = {{0,0,0,0},{0,0,0,0}};
    #pragma unroll
    for (int ntl = 0; ntl < 2; ++ntl) {
        const int nt = wave * 2 + ntl;
        #pragma unroll
        for (int ks = 0; ks < 5; ++ks) {
            s16x8 bf = *(const s16x8*)(w1 + ((nt * 5 + ks) * 64 + lane) * 8);
            acc[ntl] = __builtin_amdgcn_mfma_f32_16x16x32_bf16(a[ks], bf, acc[ntl], 0, 0, 0);
        }
    }
    #pragma unroll
    for (int ntl = 0; ntl < 2; ++ntl) {
        const int nt = wave * 2 + ntl;
        float bias = mb1[nt * 16 + r16];
        float v0 = fmaxf(acc[ntl][0] + bias, 0.f);
        float v1 = fmaxf(acc[ntl][1] + bias, 0.f);
        float v2 = fmaxf(acc[ntl][2] + bias, 0.f);
        float v3 = fmaxf(acc[ntl][3] + bias, 0.f);
        unsigned p01 = cvtpk2(v0, v1), p23 = cvtpk2(v2, v3);
        const int col = nt * 16 + r16;
        s_h1[(quad * 4 + 0) * 136 + col] = (short)p01;
        s_h1[(quad * 4 + 1) * 136 + col] = (short)(p01 >> 16);
        s_h1[(quad * 4 + 2) * 136 + col] = (short)p23;
        s_h1[(quad * 4 + 3) * 136 + col] = (short)(p23 >> 16);
    }
    __syncthreads();

    // layer2: (16x128) @ (128x64), K=128 in 4 steps; wave owns nt = wave
    s16x8 a2[4];
    #pragma unroll
    for (int ks = 0; ks < 4; ++ks)
        a2[ks] = *(const s16x8*)&s_h1[r16 * 136 + ks * 32 + quad * 8];
    f32x4 acc2 = {0,0,0,0};
    {
        const int nt = wave;
        #pragma unroll
        for (int ks = 0; ks < 4; ++ks) {
            s16x8 bf = *(const s16x8*)(w2 + ((nt * 4 + ks) * 64 + lane) * 8);
            acc2 = __builtin_amdgcn_mfma_f32_16x16x32_bf16(a2[ks], bf, acc2, 0, 0, 0);
        }
        float bias = mb2[nt * 16 + r16];
        float v0 = fmaxf(acc2[0] + bias, 0.f);
        float v1 = fmaxf(acc2[1] + bias, 0.f);
        float v2 = fmaxf(acc2[2] + bias, 0.f);
        float v3 = fmaxf(acc2[3] + bias, 0.f);
        unsigned p01 = cvtpk2(v0, v1), p23 = cvtpk2(v2, v3);
        const int col = nt * 16 + r16;
        s_h2[(quad * 4 + 0) * 72 + col] = (short)p01;
        s_h2[(quad * 4 + 1) * 72 + col] = (short)(p01 >> 16);
        s_h2[(quad * 4 + 2) * 72 + col] = (short)p23;
        s_h2[(quad * 4 + 3) * 72 + col] = (short)(p23 >> 16);
    }
    __syncthreads();

    // layer3: (16x64) @ (64x1) + sigmoid — wave 0 only
    if (wave == 0) {
        float p = 0.f;
        #pragma unroll
        for (int j = 0; j < 16; ++j)
            p += bf2f(s_h2[r16 * 72 + quad * 16 + j]) * mw3[quad * 16 + j];
        p += __shfl_xor(p, 16);
        p += __shfl_xor(p, 32);
        if (quad == 0) out[b0 + r16] = 1.f / (1.f + __expf(-(p + mb3[0])));
    }
}

extern "C" void kernel_launch(void* const* d_in, const int* in_sizes, int n_in,
                              void* d_out, int out_size, void* d_ws, size_t ws_size,
                              hipStream_t stream)
{
    const int*   item_seq  = (const int*)  d_in[0];
    // d_in[1] click_sequence: unused by the reference
    const int*   seq_len   = (const int*)  d_in[2];
    const int*   tgt_item  = (const int*)  d_in[3];
    const float* ctx_feat  = (const float*)d_in[4];
    const float* emb       = (const float*)d_in[5];
    const float* aw1 = (const float*)d_in[6];
    const float* ab1 = (const float*)d_in[7];
    const float* aw2 = (const float*)d_in[8];
    const float* ab2 = (const float*)d_in[9];
    const float* aw3 = (const float*)d_in[10];
    const float* ab3 = (const float*)d_in[11];
    const float* cw  = (const float*)d_in[12];
    const float* cb  = (const float*)d_in[13];
    const float* mw1 = (const float*)d_in[14];
    const float* mb1 = (const float*)d_in[15];
    const float* mw2 = (const float*)d_in[16];
    const float* mb2 = (const float*)d_in[17];
    const float* mw3 = (const float*)d_in[18];
    const float* mb3 = (const float*)d_in[19];
    float* out = (float*)d_out;
    short* ws  = (short*)d_ws;

    const size_t need_bytes = (size_t)(EMB_SH + EMB_ROWS * 64) * sizeof(short);
    const bool tab = ws_size >= need_bytes;

    if (tab) {
        // blocks: [0,128) qc | [128,192) weight regions | [192,3318) emb bf16 convert
        hipLaunchKernelGGL(din_prep_kernel, dim3(128 + 64 + 3126), dim3(256), 0, stream,
                           tgt_item, emb, ab1, aw1, aw2, mw1, mw2, ws);
        hipLaunchKernelGGL(din_att_v7<true>, dim3(8192), dim3(256), 0, stream,
                           item_seq, seq_len, tgt_item, ctx_feat, emb,
                           ab2, aw3, ab3, cw, cb, ws);
    } else {
        hipLaunchKernelGGL(din_prep_kernel, dim3(128 + 64), dim3(256), 0, stream,
                           tgt_item, emb, ab1, aw1, aw2, mw1, mw2, ws);
        hipLaunchKernelGGL(din_att_v7<false>, dim3(8192), dim3(256), 0, stream,
                           item_seq, seq_len, tgt_item, ctx_feat, emb,
                           ab2, aw3, ab3, cw, cb, ws);
    }
    hipLaunchKernelGGL(din_mlp_kernel, dim3(512), dim3(256), 0, stream,
                       mb1, mb2, mw3, mb3, ws, out);
}